// Round 13
// baseline (1269.414 us; speedup 1.0000x reference)
//
#include <hip/hip_runtime.h>

#define NQ 273

typedef float f4 __attribute__((ext_vector_type(4)));

// ---------------- compile-time GA tables (Cl(3,0,1) PGA, 16 blades) ----------------
struct GATab {
  int qi[NQ]; int qj[NQ]; int qk[NQ];
  float qs[NQ];
  int qgp[NQ];
  int qpath[NQ];
  int ngp, njp, nq;
};

constexpr int popc4(int m){ int c=0; for(int b=0;b<5;++b) c+=(m>>b)&1; return c; }
constexpr int swap_par(int a,int b){ int s=0; a>>=1; while(a){ s+=popc4(a&b); a>>=1; } return s&1; }

constexpr GATab make_tab(){
  GATab t{};
  int bladeOf[16]={}; int idxOf[16]={};
  { int p=0;
    for(int g=0; g<=4; ++g)
      for(int m=0; m<16; ++m)
        if(popc4(m)==g){ bladeOf[p]=m; idxOf[m]=p; ++p; }
  }
  int grade[16]={};
  for(int j=0;j<16;++j) grade[j]=popc4(bladeOf[j]);
  bool gpp[125]={}; bool jpp[125]={};
  for(int j=0;j<16;++j) for(int k=0;k<16;++k){
    int mj=bladeOf[j], mk=bladeOf[k];
    if(!(mj&mk&1)){ int i=idxOf[mj^mk]; gpp[(grade[i]*5+grade[j])*5+grade[k]]=true; }
    int cj=15^mj, ck=15^mk;
    if(!(cj&ck)){ int r=mj&mk; int i=idxOf[r]; jpp[(grade[i]*5+grade[j])*5+grade[k]]=true; }
  }
  int gpidx[125]={}; int jpidx[125]={};
  { int c=0; for(int u=0;u<125;++u){ gpidx[u] = gpp[u]? c++ : -1; } t.ngp=c; }
  { int c=0; for(int u=0;u<125;++u){ jpidx[u] = jpp[u]? c++ : -1; } t.njp=c; }
  int q=0;
  for(int j=0;j<16;++j) for(int k=0;k<16;++k){
    int mj=bladeOf[j], mk=bladeOf[k];
    if(!(mj&mk&1)){
      int i=idxOf[mj^mk];
      t.qi[q]=i; t.qj[q]=j; t.qk[q]=k;
      t.qs[q] = swap_par(mj,mk) ? -1.0f : 1.0f;
      t.qgp[q]=1;
      t.qpath[q]=gpidx[(grade[i]*5+grade[j])*5+grade[k]];
      ++q;
    }
  }
  for(int j=0;j<16;++j) for(int k=0;k<16;++k){
    int mj=bladeOf[j], mk=bladeOf[k];
    int cj=15^mj, ck=15^mk;
    if(!(cj&ck)){
      int r=mj&mk; int i=idxOf[r];
      int par = swap_par(mj,15^mj) ^ swap_par(mk,15^mk) ^ swap_par(cj,ck) ^ swap_par(r,15^r);
      t.qi[q]=i; t.qj[q]=j; t.qk[q]=k;
      t.qs[q] = par ? -1.0f : 1.0f;
      t.qgp[q]=0;
      t.qpath[q]=jpidx[(grade[i]*5+grade[j])*5+grade[k]];
      ++q;
    }
  }
  t.nq=q;
  return t;
}

constexpr GATab TAB = make_tab();
static_assert(TAB.nq == NQ, "nonzero count mismatch");
static_assert(TAB.ngp > 0 && TAB.njp > 0, "path counts");
constexpr int NGPC = TAB.ngp;
constexpr int NJPC = TAB.njp;
constexpr int NPT  = NGPC + NJPC;          // unique per-lane coef values
constexpr int PADT = (NPT + 3) & ~3;       // round to 4 for f4 loads
static_assert(NPT <= 120, "coef register file too large for 256-VGPR tier");
constexpr int GR[16] = {0,1,1,1,1,2,2,2,2,2,2,3,3,3,3,4};

// ---------------- prep kernels ----------------
// repack lin_weight (128,64,5) -> wrp[i][n][12]:
//   s in [0,5):  w1 grade s for output channel n      (o = n)
//   s in [5,10): w2 grade s-5 for output channel n+64 (o = 64+n)
//   s in [10,12): pad -> 48 B record, 3x dwordx4 per (i,n)
__global__ void prep_wrp(const float* __restrict__ linw, float* __restrict__ wrp){
  int t = blockIdx.x*blockDim.x + threadIdx.x;
  if(t < 64*64*12){
    int s = t % 12;
    int n = (t/12) & 63;
    int i = t/(12*64);
    float v = 0.f;
    if(s < 5)       v = linw[(n*64 + i)*5 + s];
    else if(s < 10) v = linw[((64+n)*64 + i)*5 + (s-5)];
    wrp[t] = v;
  }
}

// pack raw per-path coefs per lane: cco[n][p] (gp paths first, then jp, zero pad)
__global__ void prep_cco(const float* __restrict__ gpw, const float* __restrict__ jpw,
                         float* __restrict__ cco){
  int n = threadIdx.x; // blockDim = 64, grid = 1
  for(int p=0;p<NGPC;++p) cco[n*PADT + p] = gpw[n*NGPC + p];
  for(int p=0;p<NJPC;++p) cco[n*PADT + NGPC + p] = jpw[n*NJPC + p];
  for(int p=NPT;p<PADT;++p) cco[n*PADT + p] = 0.f;
}

// ---------------- main fused kernel ----------------
// The R3..R12 spill chain traced to one cause: 273 in-loop coef reads get
// hoisted by the scheduler -> live-range explosion -> scratch at ANY reg tier.
// Fix: the coef values are LOOP-INVARIANT per lane and only NPT (~68) are
// unique (273 terms share paths; signs are compile-time). Load them ONCE per
// kernel into registers; the bilinear phase becomes pure VALU (zero memory
// ops -> nothing to hoist -> structurally spill-free).
//  - 256-thr blocks -> 256-VGPR tier (R3/R6/R9/R11): creg ~68 + y 32 + acc 16
//    + w 12 + transients ~ 155 live fits.
//  - x staged in LDS (4 KB/wave, 16 KB/block), swizzled b128 writes,
//    wave-uniform broadcast f4 reads (R12, conflict-free, no rdlanes).
//  - weights stream from L2 (192 KB table, resident).
__global__ __launch_bounds__(256)
void main_k(const float* __restrict__ x, const float* __restrict__ cco,
            const float* __restrict__ wrp, float* __restrict__ out, int B){
  __shared__ float xl[4*64*16];   // 16 KB: 4 waves x (64 i x 16 v)

  const int tid  = threadIdx.x;
  const int lane = tid & 63;
  const int wv   = tid >> 6;        // 0..3
  const int n    = lane;

  // ---- load this lane's NPT path coefs into registers (once per kernel) ----
  float creg[NPT];
  {
    const f4* cp = (const f4*)(cco + n*PADT);
    #pragma unroll
    for(int k=0;k<PADT/4;++k){
      f4 a = cp[k];
      #pragma unroll
      for(int c=0;c<4;++c) if(4*k+c < NPT) creg[4*k+c] = a[c];
    }
  }

  float* xw = xl + wv*1024;        // this wave's 64x16 staging region

  for(int base = blockIdx.x*4; base < B; base += gridDim.x*4){
    const int bb = base + wv;

    // ---- stage x: lane writes its channel row (swizzled b128, bank-floor) ----
    if(bb < B){
      const f4* src = (const f4*)(x + ((long)bb*64 + lane)*16);
      #pragma unroll
      for(int r=0;r<4;++r){
        f4 a = __builtin_nontemporal_load(src+r);
        int daddr = (lane*16 + r*4) ^ ((lane&7)<<2);
        *(f4*)(xw + daddr) = a;
      }
    }
    // (per-wave region: in-wave lgkmcnt ordering suffices, no __syncthreads)

    // ---- linear phase: y1[v] = sum_i w1[g(v)]*x[i][v], y2 likewise ----
    float y1[16], y2[16];
    #pragma unroll
    for(int v=0;v<16;++v){ y1[v]=0.f; y2[v]=0.f; }

    #pragma unroll 2
    for(int i=0;i<64;++i){
      const f4* wp = (const f4*)(wrp + (i*64 + n)*12);
      f4 wa = wp[0], wb = wp[1], wc = wp[2];
      float w1[5] = {wa[0],wa[1],wa[2],wa[3],wb[0]};
      float w2[5] = {wb[1],wb[2],wb[3],wc[0],wc[1]};

      // broadcast reads of x[bb][i][0..15]: uniform address, conflict-free
      float xv[16];
      #pragma unroll
      for(int g=0;g<4;++g){
        int raddr = (i*16 + g*4) ^ ((i&7)<<2);
        f4 a = *(const f4*)(xw + raddr);
        xv[g*4+0]=a[0]; xv[g*4+1]=a[1]; xv[g*4+2]=a[2]; xv[g*4+3]=a[3];
      }

      #pragma unroll
      for(int v=0;v<16;++v){
        y1[v] = fmaf(w1[GR[v]], xv[v], y1[v]);
        y2[v] = fmaf(w2[GR[v]], xv[v], y2[v]);
      }
    }

    // ---- bilinear phase: PURE VALU (coefs in registers, signs folded) ----
    float acc[16];
    #pragma unroll
    for(int v=0;v<16;++v) acc[v]=y2[v];

    #pragma unroll
    for(int q=0;q<NQ;++q){
      const int ci = TAB.qgp[q] ? TAB.qpath[q] : (NGPC + TAB.qpath[q]);
      float c = creg[ci];                       // compile-time index -> register
      float prod = y1[TAB.qj[q]] * y2[TAB.qk[q]];
      acc[TAB.qi[q]] = fmaf((TAB.qs[q] < 0.f) ? -c : c, prod, acc[TAB.qi[q]]);
    }

    // ---- store (streamed once -> nontemporal) ----
    if(bb < B){
      f4* op = (f4*)(out + ((long)bb*64 + n)*16);
      #pragma unroll
      for(int r=0;r<4;++r){
        f4 o; o[0]=acc[4*r]; o[1]=acc[4*r+1]; o[2]=acc[4*r+2]; o[3]=acc[4*r+3];
        __builtin_nontemporal_store(o, op+r);
      }
    }
  }
}

extern "C" void kernel_launch(void* const* d_in, const int* in_sizes, int n_in,
                              void* d_out, int out_size, void* d_ws, size_t ws_size,
                              hipStream_t stream){
  const float* x    = (const float*)d_in[0];
  const float* gpw  = (const float*)d_in[1];
  const float* jpw  = (const float*)d_in[2];
  const float* linw = (const float*)d_in[3];
  float* outp = (float*)d_out;

  float* wrp = (float*)d_ws;           // 64*64*12 floats = 192 KB
  float* cco = wrp + 64*64*12;         // 64*PADT floats (~18 KB)

  int B = in_sizes[0] / (64*16);

  prep_wrp <<<192, 256, 0, stream>>>(linw, wrp);
  prep_cco <<<1,   64,  0, stream>>>(gpw, jpw, cco);
  main_k   <<<1024, 256, 0, stream>>>(x, cco, wrp, outp, B);
}

// Round 14
// 545.432 us; speedup vs baseline: 2.3274x; 2.3274x over previous
//
#include <hip/hip_runtime.h>

#define NQ 273

typedef float f4 __attribute__((ext_vector_type(4)));

// ---------------- compile-time GA tables (Cl(3,0,1) PGA, 16 blades) ----------------
struct GATab {
  int qi[NQ]; int qj[NQ]; int qk[NQ];
  float qs[NQ];
  int qgp[NQ];
  int qpath[NQ];
  int qnew[NQ];   // 1 if this term's coef index differs from previous (after sort)
  int ngp, njp, nq;
};

constexpr int popc4(int m){ int c=0; for(int b=0;b<5;++b) c+=(m>>b)&1; return c; }
constexpr int swap_par(int a,int b){ int s=0; a>>=1; while(a){ s+=popc4(a&b); a>>=1; } return s&1; }

constexpr GATab make_tab(){
  GATab t{};
  int bladeOf[16]={}; int idxOf[16]={};
  { int p=0;
    for(int g=0; g<=4; ++g)
      for(int m=0; m<16; ++m)
        if(popc4(m)==g){ bladeOf[p]=m; idxOf[m]=p; ++p; }
  }
  int grade[16]={};
  for(int j=0;j<16;++j) grade[j]=popc4(bladeOf[j]);
  bool gpp[125]={}; bool jpp[125]={};
  for(int j=0;j<16;++j) for(int k=0;k<16;++k){
    int mj=bladeOf[j], mk=bladeOf[k];
    if(!(mj&mk&1)){ int i=idxOf[mj^mk]; gpp[(grade[i]*5+grade[j])*5+grade[k]]=true; }
    int cj=15^mj, ck=15^mk;
    if(!(cj&ck)){ int r=mj&mk; int i=idxOf[r]; jpp[(grade[i]*5+grade[j])*5+grade[k]]=true; }
  }
  int gpidx[125]={}; int jpidx[125]={};
  { int c=0; for(int u=0;u<125;++u){ gpidx[u] = gpp[u]? c++ : -1; } t.ngp=c; }
  { int c=0; for(int u=0;u<125;++u){ jpidx[u] = jpp[u]? c++ : -1; } t.njp=c; }
  int q=0;
  for(int j=0;j<16;++j) for(int k=0;k<16;++k){
    int mj=bladeOf[j], mk=bladeOf[k];
    if(!(mj&mk&1)){
      int i=idxOf[mj^mk];
      t.qi[q]=i; t.qj[q]=j; t.qk[q]=k;
      t.qs[q] = swap_par(mj,mk) ? -1.0f : 1.0f;
      t.qgp[q]=1;
      t.qpath[q]=gpidx[(grade[i]*5+grade[j])*5+grade[k]];
      ++q;
    }
  }
  for(int j=0;j<16;++j) for(int k=0;k<16;++k){
    int mj=bladeOf[j], mk=bladeOf[k];
    int cj=15^mj, ck=15^mk;
    if(!(cj&ck)){
      int r=mj&mk; int i=idxOf[r];
      int par = swap_par(mj,15^mj) ^ swap_par(mk,15^mk) ^ swap_par(cj,ck) ^ swap_par(r,15^r);
      t.qi[q]=i; t.qj[q]=j; t.qk[q]=k;
      t.qs[q] = par ? -1.0f : 1.0f;
      t.qgp[q]=0;
      t.qpath[q]=jpidx[(grade[i]*5+grade[j])*5+grade[k]];
      ++q;
    }
  }
  t.nq=q;

  // sort terms by coef index (gp paths first, then jp) so terms sharing one
  // coef value are adjacent -> ONE rolling-register LDS read per unique coef
  // (~68 reads instead of 273). Sum order is free (fp reassociation ok).
  for(int a=1;a<t.nq;++a){
    int ci=t.qi[a], cj2=t.qj[a], ck2=t.qk[a], cg=t.qgp[a], cp=t.qpath[a]; float cs=t.qs[a];
    int key = cg ? cp : 1000+cp;
    int b=a-1;
    while(b>=0){
      int kb = t.qgp[b] ? t.qpath[b] : 1000+t.qpath[b];
      if(kb <= key) break;
      t.qi[b+1]=t.qi[b]; t.qj[b+1]=t.qj[b]; t.qk[b+1]=t.qk[b];
      t.qs[b+1]=t.qs[b]; t.qgp[b+1]=t.qgp[b]; t.qpath[b+1]=t.qpath[b];
      --b;
    }
    t.qi[b+1]=ci; t.qj[b+1]=cj2; t.qk[b+1]=ck2; t.qs[b+1]=cs; t.qgp[b+1]=cg; t.qpath[b+1]=cp;
  }
  for(int a=0;a<t.nq;++a){
    if(a==0){ t.qnew[a]=1; continue; }
    int ka = t.qgp[a]   ? t.qpath[a]   : 1000+t.qpath[a];
    int kb = t.qgp[a-1] ? t.qpath[a-1] : 1000+t.qpath[a-1];
    t.qnew[a] = (ka!=kb) ? 1 : 0;
  }
  return t;
}

constexpr GATab TAB = make_tab();
static_assert(TAB.nq == NQ, "nonzero count mismatch");
static_assert(TAB.ngp > 0 && TAB.njp > 0, "path counts");
constexpr int NGPC = TAB.ngp;
constexpr int NJPC = TAB.njp;
constexpr int GR[16] = {0,1,1,1,1,2,2,2,2,2,2,3,3,3,3,4};

// compact coef tables: odd-padded rows -> per-lane stride odd -> 2-way bank
// aliasing only (free, m136).
constexpr int PADG = (NGPC & 1) ? NGPC : NGPC + 1;
constexpr int PADJ = (NJPC & 1) ? NJPC : NJPC + 1;
constexpr int CGF  = 64 * PADG;          // floats
constexpr int CJF  = 64 * PADJ;          // floats
constexpr int XLF  = 8 * 64 * 16;        // x staging: 8 waves x 64 i x 16 v = 32 KB
static_assert((CGF + CJF + XLF) * 4 <= 80 * 1024, "2 blocks/CU requires <=80KB");

// ---------------- prep kernels ----------------
// repack lin_weight (128,64,5) -> wrp[i][n][12]:
//   s in [0,5):  w1 grade s for output channel n      (o = n)
//   s in [5,10): w2 grade s-5 for output channel n+64 (o = 64+n)
//   s in [10,12): pad -> 48 B record, 3x dwordx4 per (i,n)
__global__ void prep_wrp(const float* __restrict__ linw, float* __restrict__ wrp){
  int t = blockIdx.x*blockDim.x + threadIdx.x;
  if(t < 64*64*12){
    int s = t % 12;
    int n = (t/12) & 63;
    int i = t/(12*64);
    float v = 0.f;
    if(s < 5)       v = linw[(n*64 + i)*5 + s];
    else if(s < 10) v = linw[((64+n)*64 + i)*5 + (s-5)];
    wrp[t] = v;
  }
}

// pack gpw/jpw raw into odd-padded rows: cgj[n*PADG+p] , cgj[CGF + n*PADJ+p]
__global__ void prep_cpk(const float* __restrict__ gpw, const float* __restrict__ jpw,
                         float* __restrict__ cgj){
  int n = threadIdx.x; // blockDim = 64, grid = 1
  for(int p=0;p<NGPC;++p) cgj[n*PADG + p] = gpw[n*NGPC + p];
  for(int p=0;p<NJPC;++p) cgj[CGF + n*PADJ + p] = jpw[n*NJPC + p];
}

// ---------------- main fused kernel ----------------
// R12 structure (best: 727us) + targeted anti-hoist package in the bilinear:
//  - terms SORTED by coef index: rolling register c, ~68 LDS reads instead of
//    273 (4x less LDS-coef traffic, 4x fewer hoistable loads).
//  - sched_barrier(0x7) every 24 terms: ALU may cross, DS/VMEM may NOT ->
//    caps the scheduler's hoisted-load window (the R3..R12 spill source).
//    NOT mask-0 (R8's mistake: full fences force spills).
// Rest identical to R12: x staged per-wave in LDS (swizzled b128 writes,
// wave-uniform broadcast f4 reads, 0 conflicts, no rdlanes); compact raw
// coef tables (~26 KB); weights stream from L2; 512-thr blocks (realize
// more waves than 256-thr empirically: 6.7 vs 3.8 across R5..R13).
__global__ __launch_bounds__(512)
void main_k(const float* __restrict__ x, const float* __restrict__ cgj,
            const float* __restrict__ wrp, float* __restrict__ out, int B){
  __shared__ float lds[CGF + CJF + XLF];
  float* clg = lds;
  float* clj = lds + CGF;
  float* xl  = lds + CGF + CJF;

  const int tid  = threadIdx.x;
  const int lane = tid & 63;
  const int wv   = tid >> 6;        // 0..7
  const int n    = lane;

  // ---- stage compact coef tables once per block ----
  for(int idx = tid; idx < CGF + CJF; idx += 512) lds[idx] = cgj[idx];
  __syncthreads();

  const int cgbase = n*PADG;
  const int cjbase = n*PADJ;
  float* xw = xl + wv*1024;        // this wave's 64x16 staging region

  for(int base = blockIdx.x*8; base < B; base += gridDim.x*8){
    const int bb = base + wv;

    // ---- stage x: lane writes its channel row (swizzled b128, bank-floor) ----
    if(bb < B){
      const f4* src = (const f4*)(x + ((long)bb*64 + lane)*16);
      #pragma unroll
      for(int r=0;r<4;++r){
        f4 a = __builtin_nontemporal_load(src+r);
        int daddr = (lane*16 + r*4) ^ ((lane&7)<<2);
        *(f4*)(xw + daddr) = a;
      }
    }
    // (per-wave region: in-wave lgkmcnt ordering suffices, no __syncthreads)

    // ---- linear phase: y1[v] = sum_i w1[g(v)]*x[i][v], y2 likewise ----
    float y1[16], y2[16];
    #pragma unroll
    for(int v=0;v<16;++v){ y1[v]=0.f; y2[v]=0.f; }

    #pragma unroll 2
    for(int i=0;i<64;++i){
      const f4* wp = (const f4*)(wrp + (i*64 + n)*12);
      f4 wa = wp[0], wb = wp[1], wc = wp[2];
      float w1[5] = {wa[0],wa[1],wa[2],wa[3],wb[0]};
      float w2[5] = {wb[1],wb[2],wb[3],wc[0],wc[1]};

      // broadcast reads of x[bb][i][0..15]: uniform address, conflict-free
      float xv[16];
      #pragma unroll
      for(int g=0;g<4;++g){
        int raddr = (i*16 + g*4) ^ ((i&7)<<2);
        f4 a = *(const f4*)(xw + raddr);
        xv[g*4+0]=a[0]; xv[g*4+1]=a[1]; xv[g*4+2]=a[2]; xv[g*4+3]=a[3];
      }

      #pragma unroll
      for(int v=0;v<16;++v){
        y1[v] = fmaf(w1[GR[v]], xv[v], y1[v]);
        y2[v] = fmaf(w2[GR[v]], xv[v], y2[v]);
      }
    }

    // ---- bilinear phase: sorted terms, rolling coef register, capped hoist ----
    __builtin_amdgcn_sched_barrier(0x7);
    float acc[16];
    #pragma unroll
    for(int v=0;v<16;++v) acc[v]=y2[v];

    float c = 0.f;
    #pragma unroll
    for(int q=0;q<NQ;++q){
      if(TAB.qnew[q])
        c = TAB.qgp[q] ? clg[cgbase + TAB.qpath[q]] : clj[cjbase + TAB.qpath[q]];
      float prod = y1[TAB.qj[q]] * y2[TAB.qk[q]];
      acc[TAB.qi[q]] = fmaf((TAB.qs[q] < 0.f) ? -c : c, prod, acc[TAB.qi[q]]);
      if((q % 24) == 23) __builtin_amdgcn_sched_barrier(0x7);
    }
    __builtin_amdgcn_sched_barrier(0x7);

    // ---- store (streamed once -> nontemporal) ----
    if(bb < B){
      f4* op = (f4*)(out + ((long)bb*64 + n)*16);
      #pragma unroll
      for(int r=0;r<4;++r){
        f4 o; o[0]=acc[4*r]; o[1]=acc[4*r+1]; o[2]=acc[4*r+2]; o[3]=acc[4*r+3];
        __builtin_nontemporal_store(o, op+r);
      }
    }
  }
}

extern "C" void kernel_launch(void* const* d_in, const int* in_sizes, int n_in,
                              void* d_out, int out_size, void* d_ws, size_t ws_size,
                              hipStream_t stream){
  const float* x    = (const float*)d_in[0];
  const float* gpw  = (const float*)d_in[1];
  const float* jpw  = (const float*)d_in[2];
  const float* linw = (const float*)d_in[3];
  float* outp = (float*)d_out;

  float* wrp = (float*)d_ws;           // 64*64*12 floats = 192 KB
  float* cgj = wrp + 64*64*12;         // CGF+CJF floats (~26 KB)

  int B = in_sizes[0] / (64*16);

  prep_wrp <<<192, 256, 0, stream>>>(linw, wrp);
  prep_cpk <<<1,   64,  0, stream>>>(gpw, jpw, cgj);
  main_k   <<<1024, 512, 0, stream>>>(x, cgj, wrp, outp, B);
}